// Round 9
// baseline (669.809 us; speedup 1.0000x reference)
//
#include <hip/hip_runtime.h>
#include <hip/hip_bf16.h>

// KNN top-16: X_test[4096,256] vs X_train[65536,256], fp32 in, int32 idx out.
// Phase 1: fp32->bf16 convert; fp32 train row sq-norms (numpy-pairwise emulation).
// Phase 2: bf16 MFMA approx score GEMM (v = ||b||^2 - 2 a.b). EXACT R4 kernel
//          (proven 380us champion: 128x128 block tile, 8 waves/512thr, wave-tile
//          32x64, A preloaded, single-buffer stage->__syncthreads->compute,
//          block-wide push selection QCAP=12) with ONE token changed:
//          __launch_bounds__(512,4) -> (512,6). LDS 50176*3=150.5KB <= 160KB and
//          VGPR 64 <= 512/6=85, so 3 blocks/CU (24 waves) can now co-reside vs 2.
//          Theory: R4 is latency-chain-bound (28K cy/iter wall, no pipe >30%);
//          a 3rd resident block overlaps the serial stage-wait+barrier chains.
//          R8 lesson: selection internals perturb inter-block lockstep -> L2
//          panel locality collapses (FETCH 228->970MB). So: touch NOTHING else.
// Phase 3: 8 rows/block: approx-top-32 prefilter of 256 candidates (width-32
//          shuffles), then 256 parallel exact fp32-reference-emulating chains,
//          lex (d32, gidx) top-16 (fp32 snap-ties resolve by index like top_k).

typedef short bf16x8 __attribute__((ext_vector_type(8)));
typedef float f32x4 __attribute__((ext_vector_type(4)));
typedef unsigned short ushort_t;
typedef unsigned long long u64;

#define K_DIM     256
#define N_TRAIN   65536
#define N_TEST    4096
#define TM        128
#define TN        128
#define NCHUNK    16
#define CHUNK_N   (N_TRAIN / NCHUNK)      // 4096
#define ITERS     (CHUNK_N / TN)          // 32
#define LISTN     16
#define LISTP     17                       // padded stride
#define QCAP      12
#define QCAPP     13                       // padded stride
#define RPB       8                        // refine rows per block

// ---------------- numpy pairwise sum emulation (fp32, contract OFF) ----------------
static __device__ __forceinline__ float np_pw_sq128(const float* __restrict__ x) {
    #pragma clang fp contract(off)
    float r0, r1, r2, r3, r4, r5, r6, r7;
    {
        const float4 a = *(const float4*)(x + 0);
        const float4 b = *(const float4*)(x + 4);
        r0 = a.x * a.x; r1 = a.y * a.y; r2 = a.z * a.z; r3 = a.w * a.w;
        r4 = b.x * b.x; r5 = b.y * b.y; r6 = b.z * b.z; r7 = b.w * b.w;
    }
    for (int i = 8; i < 128; i += 8) {
        const float4 a = *(const float4*)(x + i);
        const float4 b = *(const float4*)(x + i + 4);
        r0 = r0 + a.x * a.x; r1 = r1 + a.y * a.y;
        r2 = r2 + a.z * a.z; r3 = r3 + a.w * a.w;
        r4 = r4 + b.x * b.x; r5 = r5 + b.y * b.y;
        r6 = r6 + b.z * b.z; r7 = r7 + b.w * b.w;
    }
    return ((r0 + r1) + (r2 + r3)) + ((r4 + r5) + (r6 + r7));
}

// ---------------- async global->LDS, 16B per lane ----------------
static __device__ __forceinline__ void gld_lds16(const ushort_t* g, ushort_t* l) {
    __builtin_amdgcn_global_load_lds(
        (const __attribute__((address_space(1))) unsigned int*)g,
        (__attribute__((address_space(3))) unsigned int*)l,
        16, 0, 0);
}

// ---------------- Phase 1a: convert ----------------
static __device__ __forceinline__ ushort_t f2bf(float x) {
    unsigned u = __float_as_uint(x);
    return (ushort_t)((u + 0x7FFFu + ((u >> 16) & 1u)) >> 16);  // RNE
}

__global__ __launch_bounds__(256) void convert_bf16(
    const float* __restrict__ src, ushort_t* __restrict__ dst, int nrows)
{
    const int wid = threadIdx.x >> 6, lane = threadIdx.x & 63;
    const int row = blockIdx.x * 4 + wid;
    if (row >= nrows) return;
    const float4 f = *(const float4*)(src + (size_t)row * K_DIM + lane * 4);
    ushort4 h;
    h.x = f2bf(f.x); h.y = f2bf(f.y); h.z = f2bf(f.z); h.w = f2bf(f.w);
    *(ushort4*)(dst + (size_t)row * K_DIM + lane * 4) = h;
}

// ---------------- Phase 1b: train row norms, numpy-pairwise fp32 ----------------
__global__ __launch_bounds__(256) void train_sq_np(
    const float* __restrict__ train, float* __restrict__ bsq)
{
    const int r = blockIdx.x * 256 + threadIdx.x;
    const float* x = train + (size_t)r * K_DIM;
    bsq[r] = np_pw_sq128(x) + np_pw_sq128(x + 128);
}

// ---------------- Phase 2: approx GEMM + push-based per-row top-16 ----------------
// 512 thr, 4x2 wave grid, wave-tile 32x64. A in registers (64 VGPR), B in 32 KB LDS.
__global__ __launch_bounds__(512, 6) void knn_approx(
    const ushort_t* __restrict__ testBf, const ushort_t* __restrict__ trainBf,
    const float* __restrict__ bsq, unsigned* __restrict__ cand)
{
    __shared__ __align__(16) ushort_t sB[TN * 128];    // 32 KB: 128 cols x 128 k
    __shared__ __align__(16) unsigned sLv[TM * LISTP]; // 8.5 KB padded top-16 lists
    __shared__ unsigned sQ  [TM * QCAPP];              // 6.5 KB padded queues
    __shared__ int      sQn [TM];
    __shared__ unsigned sCutP[TM];
    __shared__ float    sBsq[TN];

    const int tid = threadIdx.x;
    const int bx = blockIdx.x;
    const int chunk = bx & (NCHUNK - 1);               // bx%8 = chunk%8 -> chunk-per-XCD
    const int rowTile = bx >> 4;                       // 0..31
    const int rowBase = rowTile * TM;
    const int chunkBase = chunk * CHUNK_N;
    const int lane = tid & 63;
    const int wid = tid >> 6;                          // 0..7
    const int quad = lane >> 4;
    const int l15 = lane & 15;
    const int wm = wid >> 1;           // 0..3 (row 32-group)
    const int wn = wid & 1;            // 0..1 (col 64-half)

    if (tid < TM) {
        sQn[tid] = 0;
        sCutP[tid] = 0xFFFFFFFFu;
        #pragma unroll
        for (int j = 0; j < LISTN; ++j)
            sLv[tid * LISTP + j] = 0xFFFFF000u | (unsigned)j;   // sentinel keys
    }

    // ---- preload ALL A-fragments into registers (once; 64 VGPR) ----
    bf16x8 af[2][2][4];   // [im][panel][s2]
    {
        const ushort_t* a0 = testBf + (size_t)(rowBase + wm * 32 + l15) * K_DIM + quad * 8;
        const ushort_t* a1 = a0 + (size_t)16 * K_DIM;
        #pragma unroll
        for (int p = 0; p < 2; ++p)
            #pragma unroll
            for (int s2 = 0; s2 < 4; ++s2) {
                af[0][p][s2] = *(const bf16x8*)(a0 + p * 128 + s2 * 32);
                af[1][p][s2] = *(const bf16x8*)(a1 + p * 128 + s2 * 32);
            }
    }

    // B staging: slot s = c*512+tid -> col = c*32 + (tid>>4), group u = tid&15
    const int rt = tid >> 4;                           // 0..31
    const int ub = tid & 15;
    const int kg = ((ub & 7) ^ (rt & 7)) | (ub & 8);   // c-independent (32%8==0)

    for (int it = 0; it < ITERS; ++it) {
        const int colBase = chunkBase + it * TN;
        f32x4 acc[2][4] = {};

        #pragma unroll
        for (int p = 0; p < 2; ++p) {
            if (p) __syncthreads();    // protect sB against prior panel's reads
            {
                const ushort_t* gb = trainBf + (size_t)(colBase + rt) * K_DIM + p * 128 + kg * 8;
                ushort_t* lb = sB + (size_t)tid * 8;
                #pragma unroll
                for (int c = 0; c < 4; ++c)
                    gld_lds16(gb + (size_t)c * 32 * K_DIM, lb + (size_t)c * 4096);
            }
            if (p == 0 && tid < TN) sBsq[tid] = bsq[colBase + tid];
            __syncthreads();           // drains vmcnt -> LDS valid

            #pragma unroll
            for (int s2 = 0; s2 < 4; ++s2) {
                #pragma unroll
                for (int in = 0; in < 4; ++in) {
                    const int col = wn * 64 + in * 16 + l15;
                    const int g = s2 * 4 + quad;
                    const int pg = ((g & 7) ^ (col & 7)) | (g & 8);
                    const bf16x8 bfr = *(const bf16x8*)(sB + (size_t)col * 128 + pg * 8);
                    acc[0][in] = __builtin_amdgcn_mfma_f32_16x16x32_bf16(af[0][p][s2], bfr, acc[0][in], 0, 0, 0);
                    acc[1][in] = __builtin_amdgcn_mfma_f32_16x16x32_bf16(af[1][p][s2], bfr, acc[1][in], 0, 0, 0);
                }
            }
        }

        // v = bsq[col] - 2*dot; C layout: row=quad*4+r, col=l15
        float bq[4];
        unsigned cpk[4];
        #pragma unroll
        for (int in = 0; in < 4; ++in) {
            bq[in] = sBsq[wn * 64 + in * 16 + l15];
            cpk[in] = (unsigned)(it * TN + wn * 64 + in * 16 + l15);   // 12-bit col-in-chunk
        }
        #pragma unroll
        for (int im = 0; im < 2; ++im)
            #pragma unroll
            for (int in = 0; in < 4; ++in)
                #pragma unroll
                for (int r = 0; r < 4; ++r)
                    acc[im][in][r] = fmaf(-2.0f, acc[im][in][r], bq[in]);

        // ---- push-based selection on packed keys; bounded retry rounds ----
        unsigned pend = 0xFFFFFFFFu;               // 32 values/thread
        while (true) {
            unsigned cutr[2][4];
            #pragma unroll
            for (int im = 0; im < 2; ++im)
                #pragma unroll
                for (int r = 0; r < 4; ++r)
                    cutr[im][r] = sCutP[wm * 32 + im * 16 + quad * 4 + r];

            unsigned np = 0u;
            #pragma unroll
            for (int im = 0; im < 2; ++im)
                #pragma unroll
                for (int in = 0; in < 4; ++in)
                    #pragma unroll
                    for (int r = 0; r < 4; ++r) {
                        const int bit = (im * 4 + in) * 4 + r;
                        if ((pend >> bit) & 1u) {
                            const unsigned key =
                                (__float_as_uint(acc[im][in][r] + 1024.0f) & 0xFFFFF000u) | cpk[in];
                            if (key < cutr[im][r]) {
                                const int row = wm * 32 + im * 16 + quad * 4 + r;
                                const int pos = atomicAdd(&sQn[row], 1);
                                if (pos < QCAP) sQ[row * QCAPP + pos] = key;
                                else            np |= (1u << bit);
                            }
                        }
                    }
            __syncthreads();                       // pushes done before drain
            if (tid < TM) {
                const int n = min(sQn[tid], QCAP);
                if (n > 0) {                       // empty queue (steady state) -> skip
                    unsigned lk[LISTN];            // transient regs: 4x ds_read_b128
                    #pragma unroll
                    for (int j = 0; j < LISTN; ++j) lk[j] = sLv[tid * LISTP + j];
                    for (int e = 0; e < n; ++e) {
                        const unsigned k = sQ[tid * QCAPP + e];
                        if (k < lk[LISTN - 1]) {
                            lk[LISTN - 1] = k;
                            #pragma unroll
                            for (int j = LISTN - 1; j > 0; --j)
                                if (lk[j] < lk[j - 1]) {
                                    const unsigned t = lk[j]; lk[j] = lk[j - 1]; lk[j - 1] = t;
                                }
                        }
                    }
                    #pragma unroll
                    for (int j = 0; j < LISTN; ++j) sLv[tid * LISTP + j] = lk[j];
                    sQn[tid] = 0;
                    sCutP[tid] = lk[LISTN - 1];
                }
            }
            if (!__syncthreads_or(np != 0u)) break;   // also publishes sCutP/sQn
            pend = np;
        }
    }

    if (tid < TM) {
        #pragma unroll
        for (int j = 0; j < LISTN; ++j)
            cand[(size_t)(rowBase + tid) * (NCHUNK * LISTN) + chunk * LISTN + j] =
                sLv[tid * LISTP + j];
    }
}

// ---------------- Phase 3: prefilter 256->32 + parallel exact fp32 re-rank ----------------
// 8 rows/block, 32 lanes/row; width-32 shuffles.
__global__ __launch_bounds__(256) void knn_refine(
    const float* __restrict__ test, const float* __restrict__ train,
    const float* __restrict__ bsq, const unsigned* __restrict__ cand,
    int* __restrict__ out)
{
    __shared__ __align__(16) float sArow[RPB * K_DIM];   // 8 KB
    __shared__ int sSel[RPB * 32];                       // 1 KB

    const int tid = threadIdx.x;
    const int rowBase = blockIdx.x * RPB;
    const int r = tid >> 5;          // row 0..7
    const int sub = tid & 31;        // lane within row

    {
        const float4* src = (const float4*)(test + (size_t)rowBase * K_DIM);
        float4* dst = (float4*)sArow;
        dst[tid] = src[tid];
        dst[256 + tid] = src[256 + tid];
    }

    u64 ek[8];
    {
        const unsigned* cp = cand + (size_t)(rowBase + r) * 256 + sub * 8;
        #pragma unroll
        for (int j = 0; j < 8; ++j) {
            const unsigned k = cp[j];
            const int chunkId = (sub * 8 + j) >> 4;
            const unsigned gidx = (unsigned)(chunkId * CHUNK_N) + (k & 0xFFFu);
            ek[j] = ((u64)(k & 0xFFFFF000u) << 8) | gidx;
        }
    }
    __syncthreads();

    for (int sel = 0; sel < 32; ++sel) {
        u64 bk = ek[0];
        #pragma unroll
        for (int j = 1; j < 8; ++j) bk = (ek[j] < bk) ? ek[j] : bk;
        #pragma unroll
        for (int off = 16; off > 0; off >>= 1) {
            const u64 ok = __shfl_xor(bk, off, 32);
            bk = (ok < bk) ? ok : bk;
        }
        if (sub == 0) sSel[r * 32 + sel] = (int)(bk & 0xFFFFULL);
        #pragma unroll
        for (int j = 0; j < 8; ++j)
            if (ek[j] == bk) ek[j] = ~0ULL;
    }
    __syncthreads();

    const int gidx = sSel[r * 32 + sub];
    const float* arow = sArow + r * K_DIM;
    const float ta = np_pw_sq128(arow) + np_pw_sq128(arow + 128);
    const float tb = bsq[gidx];

    const float4* bp = (const float4*)(train + (size_t)gidx * K_DIM);
    const float4* ap = (const float4*)arow;
    float c = 0.0f;
    #pragma unroll 8
    for (int k = 0; k < K_DIM / 4; ++k) {
        const float4 a = ap[k];
        const float4 b = bp[k];
        c = fmaf(a.x, b.x, c); c = fmaf(a.y, b.y, c);
        c = fmaf(a.z, b.z, c); c = fmaf(a.w, b.w, c);
    }
    float d32;
    {
        #pragma clang fp contract(off)
        const float t = ta + tb;
        float s = t - 2.0f * c;
        s = fmaxf(s, 0.0f);
        d32 = sqrtf(s);
    }

    u64 fk = ((u64)__float_as_uint(d32) << 32) | (unsigned)gidx;
    for (int sel = 0; sel < 16; ++sel) {
        u64 bk = fk;
        #pragma unroll
        for (int off = 16; off > 0; off >>= 1) {
            const u64 ok = __shfl_xor(bk, off, 32);
            bk = (ok < bk) ? ok : bk;
        }
        if (sub == 0) out[(size_t)(rowBase + r) * 16 + sel] = (int)(bk & 0xFFFFFFFFULL);
        if (fk == bk) fk = ~0ULL;
    }
}

// ---------------- launch ----------------
extern "C" void kernel_launch(void* const* d_in, const int* in_sizes, int n_in,
                              void* d_out, int out_size, void* d_ws, size_t ws_size,
                              hipStream_t stream)
{
    const float* Xtrain = (const float*)d_in[0];   // [65536, 256]
    const float* Xtest  = (const float*)d_in[1];   // [4096, 256]
    int* out = (int*)d_out;                        // [4096, 16] int32

    const size_t OFF_TRAINBF = 0;                              // 33,554,432 B
    const size_t OFF_TESTBF  = 33554432;                       //  2,097,152 B
    const size_t OFF_BSQ     = 35651584;                       //    262,144 B
    const size_t OFF_CAND    = 35913728;                       //  4,194,304 B
    const size_t NEED        = 40108032;
    if (ws_size < NEED) return;

    char* ws = (char*)d_ws;
    ushort_t* trainBf = (ushort_t*)(ws + OFF_TRAINBF);
    ushort_t* testBf  = (ushort_t*)(ws + OFF_TESTBF);
    float*    bsq     = (float*)(ws + OFF_BSQ);
    unsigned* cand    = (unsigned*)(ws + OFF_CAND);

    convert_bf16<<<dim3(N_TRAIN / 4), dim3(256), 0, stream>>>(Xtrain, trainBf, N_TRAIN);
    convert_bf16<<<dim3(N_TEST / 4), dim3(256), 0, stream>>>(Xtest, testBf, N_TEST);
    train_sq_np<<<dim3(N_TRAIN / 256), dim3(256), 0, stream>>>(Xtrain, bsq);
    knn_approx<<<dim3((N_TEST / TM) * NCHUNK), dim3(512), 0, stream>>>(testBf, trainBf, bsq, cand);
    knn_refine<<<dim3(N_TEST / RPB), dim3(256), 0, stream>>>(Xtest, Xtrain, bsq, cand, out);
}

// Round 10
// 542.074 us; speedup vs baseline: 1.2356x; 1.2356x over previous
//
#include <hip/hip_runtime.h>
#include <hip/hip_bf16.h>

// KNN top-16: X_test[4096,256] vs X_train[65536,256], fp32 in, int32 idx out.
// Phase 1: fp32->bf16 convert; fp32 train row sq-norms (numpy-pairwise emulation).
// Phase 2: bf16 MFMA approx score GEMM (v = ||b||^2 - 2 a.b) with SWAPPED MFMA
//          OPERANDS: mfma(train_frag, test_frag, acc) -> D[train_col][test_row].
//          Each thread owns ONE test row (l15) and 32 train cols/iter
//          (ct*16+quad*4+r) -> per-row top-16 kept in 16 REGISTERS per thread.
//          Selection protocol (atomics, queues, drain, retries, 2+ syncs/iter)
//          DELETED -- per value: fmaf+pack+cmp, rare in-register insertion.
//          Exact per-quad partitions merged once at chunk end via shfl_xor
//          (16,32) + bitonic min-merge (min(A[i],B[15-i]) = smallest-16) +
//          4-stage bitonic sort. Staging/GEMM/syncs otherwise R4-identical
//          (proven 380us; R2/R5-R9 all regressed). Wave = 16 rows x 128 cols:
//          bfr reads double to 64/iter/wave (LDS ~45%, the predicted new wall).
//          VGPR ~ af 32 + acc 32 + lk 16 ~ 110; LDS 33 KB; launch_bounds(512,4)
//          (R9 lesson: never force waves beyond the register working set).
// Phase 3: 8 rows/block: approx-top-32 prefilter of 256 candidates (width-32
//          shuffles), then 256 parallel exact fp32-reference-emulating chains,
//          lex (d32, gidx) top-16 (fp32 snap-ties resolve by index like top_k).

typedef short bf16x8 __attribute__((ext_vector_type(8)));
typedef float f32x4 __attribute__((ext_vector_type(4)));
typedef unsigned short ushort_t;
typedef unsigned long long u64;

#define K_DIM     256
#define N_TRAIN   65536
#define N_TEST    4096
#define TM        128
#define TN        128
#define NCHUNK    16
#define CHUNK_N   (N_TRAIN / NCHUNK)      // 4096
#define ITERS     (CHUNK_N / TN)          // 32
#define LISTN     16
#define RPB       8                        // refine rows per block

// ---------------- numpy pairwise sum emulation (fp32, contract OFF) ----------------
static __device__ __forceinline__ float np_pw_sq128(const float* __restrict__ x) {
    #pragma clang fp contract(off)
    float r0, r1, r2, r3, r4, r5, r6, r7;
    {
        const float4 a = *(const float4*)(x + 0);
        const float4 b = *(const float4*)(x + 4);
        r0 = a.x * a.x; r1 = a.y * a.y; r2 = a.z * a.z; r3 = a.w * a.w;
        r4 = b.x * b.x; r5 = b.y * b.y; r6 = b.z * b.z; r7 = b.w * b.w;
    }
    for (int i = 8; i < 128; i += 8) {
        const float4 a = *(const float4*)(x + i);
        const float4 b = *(const float4*)(x + i + 4);
        r0 = r0 + a.x * a.x; r1 = r1 + a.y * a.y;
        r2 = r2 + a.z * a.z; r3 = r3 + a.w * a.w;
        r4 = r4 + b.x * b.x; r5 = r5 + b.y * b.y;
        r6 = r6 + b.z * b.z; r7 = r7 + b.w * b.w;
    }
    return ((r0 + r1) + (r2 + r3)) + ((r4 + r5) + (r6 + r7));
}

// ---------------- async global->LDS, 16B per lane ----------------
static __device__ __forceinline__ void gld_lds16(const ushort_t* g, ushort_t* l) {
    __builtin_amdgcn_global_load_lds(
        (const __attribute__((address_space(1))) unsigned int*)g,
        (__attribute__((address_space(3))) unsigned int*)l,
        16, 0, 0);
}

// ---------------- Phase 1a: convert ----------------
static __device__ __forceinline__ ushort_t f2bf(float x) {
    unsigned u = __float_as_uint(x);
    return (ushort_t)((u + 0x7FFFu + ((u >> 16) & 1u)) >> 16);  // RNE
}

__global__ __launch_bounds__(256) void convert_bf16(
    const float* __restrict__ src, ushort_t* __restrict__ dst, int nrows)
{
    const int wid = threadIdx.x >> 6, lane = threadIdx.x & 63;
    const int row = blockIdx.x * 4 + wid;
    if (row >= nrows) return;
    const float4 f = *(const float4*)(src + (size_t)row * K_DIM + lane * 4);
    ushort4 h;
    h.x = f2bf(f.x); h.y = f2bf(f.y); h.z = f2bf(f.z); h.w = f2bf(f.w);
    *(ushort4*)(dst + (size_t)row * K_DIM + lane * 4) = h;
}

// ---------------- Phase 1b: train row norms, numpy-pairwise fp32 ----------------
__global__ __launch_bounds__(256) void train_sq_np(
    const float* __restrict__ train, float* __restrict__ bsq)
{
    const int r = blockIdx.x * 256 + threadIdx.x;
    const float* x = train + (size_t)r * K_DIM;
    bsq[r] = np_pw_sq128(x) + np_pw_sq128(x + 128);
}

// ---------------- Phase 2: swapped-operand GEMM + register-resident top-16 ----------------
// 512 thr, 8 waves; each wave owns 16 test rows x 128 train cols. B (train) staged
// in 32 KB LDS exactly as R4; A (test) preloaded; D[train_col][test_row].
__global__ __launch_bounds__(512, 4) void knn_approx(
    const ushort_t* __restrict__ testBf, const ushort_t* __restrict__ trainBf,
    const float* __restrict__ bsq, unsigned* __restrict__ cand)
{
    __shared__ __align__(16) ushort_t sB[TN * 128];    // 32 KB: 128 cols x 128 k
    __shared__ __align__(16) float    sBsq[TN];        // 512 B

    const int tid = threadIdx.x;
    const int bx = blockIdx.x;
    const int chunk = bx & (NCHUNK - 1);               // bx%8 = chunk%8 -> chunk-per-XCD
    const int rowTile = bx >> 4;                       // 0..31
    const int rowBase = rowTile * TM;
    const int chunkBase = chunk * CHUNK_N;
    const int lane = tid & 63;
    const int wid = tid >> 6;                          // 0..7
    const int quad = lane >> 4;
    const int l15 = lane & 15;

    // my test row (one per thread; 16 rows per wave, 8 waves = 128 rows)
    const int myRow = rowBase + wid * 16 + l15;

    // register-resident top-16 (packed keys), ascending; sentinels > any real key
    unsigned lk[LISTN];
    #pragma unroll
    for (int j = 0; j < LISTN; ++j) lk[j] = 0xFFFFF000u | (unsigned)j;

    // ---- preload A-fragments (test row myRow, all K=256; 8 frags = 32 VGPR) ----
    bf16x8 af[2][4];   // [panel][s2]; frag k = quad*8 + s2*32 + p*128
    {
        const ushort_t* a0 = testBf + (size_t)myRow * K_DIM + quad * 8;
        #pragma unroll
        for (int p = 0; p < 2; ++p)
            #pragma unroll
            for (int s2 = 0; s2 < 4; ++s2)
                af[p][s2] = *(const bf16x8*)(a0 + p * 128 + s2 * 32);
    }

    // B staging (R4-identical): slot s = c*512+tid -> col = c*32 + (tid>>4)
    const int rt = tid >> 4;                           // 0..31
    const int ub = tid & 15;
    const int kg = ((ub & 7) ^ (rt & 7)) | (ub & 8);   // c-independent (32%8==0)

    for (int it = 0; it < ITERS; ++it) {
        const int colBase = chunkBase + it * TN;
        f32x4 acc[8] = {};                             // 8 ct-tiles x 4 cols, my row

        #pragma unroll
        for (int p = 0; p < 2; ++p) {
            __syncthreads();           // protect sB against prior panel's reads
            {
                const ushort_t* gb = trainBf + (size_t)(colBase + rt) * K_DIM + p * 128 + kg * 8;
                ushort_t* lb = sB + (size_t)tid * 8;
                #pragma unroll
                for (int c = 0; c < 4; ++c)
                    gld_lds16(gb + (size_t)c * 32 * K_DIM, lb + (size_t)c * 4096);
            }
            if (p == 0 && tid < TN) sBsq[tid] = bsq[colBase + tid];
            __syncthreads();           // drains vmcnt -> LDS valid

            #pragma unroll
            for (int s2 = 0; s2 < 4; ++s2) {
                #pragma unroll
                for (int ct = 0; ct < 8; ++ct) {
                    const int col = ct * 16 + l15;     // train col (A-operand row)
                    const int g = s2 * 4 + quad;
                    const int pg = ((g & 7) ^ (col & 7)) | (g & 8);
                    const bf16x8 bfr = *(const bf16x8*)(sB + (size_t)col * 128 + pg * 8);
                    // SWAPPED: train as A, test as B -> D[train_col][test_row]
                    acc[ct] = __builtin_amdgcn_mfma_f32_16x16x32_bf16(bfr, af[p][s2], acc[ct], 0, 0, 0);
                }
            }
        }

        // epilogue: v = bsq[col] - 2*dot for my row; cols = ct*16 + quad*4 + r
        #pragma unroll
        for (int ct = 0; ct < 8; ++ct) {
            const float4 bq4 = *(const float4*)(sBsq + ct * 16 + quad * 4);
            const unsigned colb = (unsigned)(it * TN + ct * 16 + quad * 4);
            #pragma unroll
            for (int r = 0; r < 4; ++r) {
                const float bq = (r == 0) ? bq4.x : (r == 1) ? bq4.y : (r == 2) ? bq4.z : bq4.w;
                const float v = fmaf(-2.0f, acc[ct][r], bq);
                const unsigned key =
                    (__float_as_uint(v + 1024.0f) & 0xFFFFF000u) | (colb + (unsigned)r);
                if (key < lk[LISTN - 1]) {             // register insertion (rare)
                    lk[LISTN - 1] = key;
                    #pragma unroll
                    for (int j = LISTN - 1; j > 0; --j)
                        if (lk[j] < lk[j - 1]) {
                            const unsigned t = lk[j]; lk[j] = lk[j - 1]; lk[j - 1] = t;
                        }
                }
            }
        }
    }

    // ---- merge the 4 quad-partitions of my row (exact): shfl_xor 16 then 32 ----
    #pragma unroll
    for (int step = 16; step <= 32; step <<= 1) {
        unsigned other[LISTN];
        #pragma unroll
        for (int j = 0; j < LISTN; ++j)
            other[j] = (unsigned)__shfl_xor((int)lk[j], step, 64);
        unsigned c[LISTN];
        // half-cleaner: smallest 16 of (lk ∪ other); result is bitonic
        #pragma unroll
        for (int j = 0; j < LISTN; ++j) {
            const unsigned a = lk[j], b = other[LISTN - 1 - j];
            c[j] = a < b ? a : b;
        }
        // bitonic sort of a bitonic sequence: stages d = 8,4,2,1
        #pragma unroll
        for (int d = 8; d >= 1; d >>= 1)
            #pragma unroll
            for (int j = 0; j < LISTN; ++j)
                if ((j & d) == 0) {
                    const unsigned x = c[j], y = c[j | d];
                    c[j] = x < y ? x : y;
                    c[j | d] = x < y ? y : x;
                }
        #pragma unroll
        for (int j = 0; j < LISTN; ++j) lk[j] = c[j];
    }

    // quad 0 lanes hold the final sorted top-16 for their row
    if (lane < 16) {
        unsigned* dst = cand + (size_t)myRow * (NCHUNK * LISTN) + chunk * LISTN;
        #pragma unroll
        for (int j = 0; j < LISTN; ++j) dst[j] = lk[j];
    }
}

// ---------------- Phase 3: prefilter 256->32 + parallel exact fp32 re-rank ----------------
// 8 rows/block, 32 lanes/row; width-32 shuffles.
__global__ __launch_bounds__(256) void knn_refine(
    const float* __restrict__ test, const float* __restrict__ train,
    const float* __restrict__ bsq, const unsigned* __restrict__ cand,
    int* __restrict__ out)
{
    __shared__ __align__(16) float sArow[RPB * K_DIM];   // 8 KB
    __shared__ int sSel[RPB * 32];                       // 1 KB

    const int tid = threadIdx.x;
    const int rowBase = blockIdx.x * RPB;
    const int r = tid >> 5;          // row 0..7
    const int sub = tid & 31;        // lane within row

    {
        const float4* src = (const float4*)(test + (size_t)rowBase * K_DIM);
        float4* dst = (float4*)sArow;
        dst[tid] = src[tid];
        dst[256 + tid] = src[256 + tid];
    }

    u64 ek[8];
    {
        const unsigned* cp = cand + (size_t)(rowBase + r) * 256 + sub * 8;
        #pragma unroll
        for (int j = 0; j < 8; ++j) {
            const unsigned k = cp[j];
            const int chunkId = (sub * 8 + j) >> 4;
            const unsigned gidx = (unsigned)(chunkId * CHUNK_N) + (k & 0xFFFu);
            ek[j] = ((u64)(k & 0xFFFFF000u) << 8) | gidx;
        }
    }
    __syncthreads();

    for (int sel = 0; sel < 32; ++sel) {
        u64 bk = ek[0];
        #pragma unroll
        for (int j = 1; j < 8; ++j) bk = (ek[j] < bk) ? ek[j] : bk;
        #pragma unroll
        for (int off = 16; off > 0; off >>= 1) {
            const u64 ok = __shfl_xor(bk, off, 32);
            bk = (ok < bk) ? ok : bk;
        }
        if (sub == 0) sSel[r * 32 + sel] = (int)(bk & 0xFFFFULL);
        #pragma unroll
        for (int j = 0; j < 8; ++j)
            if (ek[j] == bk) ek[j] = ~0ULL;
    }
    __syncthreads();

    const int gidx = sSel[r * 32 + sub];
    const float* arow = sArow + r * K_DIM;
    const float ta = np_pw_sq128(arow) + np_pw_sq128(arow + 128);
    const float tb = bsq[gidx];

    const float4* bp = (const float4*)(train + (size_t)gidx * K_DIM);
    const float4* ap = (const float4*)arow;
    float c = 0.0f;
    #pragma unroll 8
    for (int k = 0; k < K_DIM / 4; ++k) {
        const float4 a = ap[k];
        const float4 b = bp[k];
        c = fmaf(a.x, b.x, c); c = fmaf(a.y, b.y, c);
        c = fmaf(a.z, b.z, c); c = fmaf(a.w, b.w, c);
    }
    float d32;
    {
        #pragma clang fp contract(off)
        const float t = ta + tb;
        float s = t - 2.0f * c;
        s = fmaxf(s, 0.0f);
        d32 = sqrtf(s);
    }

    u64 fk = ((u64)__float_as_uint(d32) << 32) | (unsigned)gidx;
    for (int sel = 0; sel < 16; ++sel) {
        u64 bk = fk;
        #pragma unroll
        for (int off = 16; off > 0; off >>= 1) {
            const u64 ok = __shfl_xor(bk, off, 32);
            bk = (ok < bk) ? ok : bk;
        }
        if (sub == 0) out[(size_t)(rowBase + r) * 16 + sel] = (int)(bk & 0xFFFFFFFFULL);
        if (fk == bk) fk = ~0ULL;
    }
}

// ---------------- launch ----------------
extern "C" void kernel_launch(void* const* d_in, const int* in_sizes, int n_in,
                              void* d_out, int out_size, void* d_ws, size_t ws_size,
                              hipStream_t stream)
{
    const float* Xtrain = (const float*)d_in[0];   // [65536, 256]
    const float* Xtest  = (const float*)d_in[1];   // [4096, 256]
    int* out = (int*)d_out;                        // [4096, 16] int32

    const size_t OFF_TRAINBF = 0;                              // 33,554,432 B
    const size_t OFF_TESTBF  = 33554432;                       //  2,097,152 B
    const size_t OFF_BSQ     = 35651584;                       //    262,144 B
    const size_t OFF_CAND    = 35913728;                       //  4,194,304 B
    const size_t NEED        = 40108032;
    if (ws_size < NEED) return;

    char* ws = (char*)d_ws;
    ushort_t* trainBf = (ushort_t*)(ws + OFF_TRAINBF);
    ushort_t* testBf  = (ushort_t*)(ws + OFF_TESTBF);
    float*    bsq     = (float*)(ws + OFF_BSQ);
    unsigned* cand    = (unsigned*)(ws + OFF_CAND);

    convert_bf16<<<dim3(N_TRAIN / 4), dim3(256), 0, stream>>>(Xtrain, trainBf, N_TRAIN);
    convert_bf16<<<dim3(N_TEST / 4), dim3(256), 0, stream>>>(Xtest, testBf, N_TEST);
    train_sq_np<<<dim3(N_TRAIN / 256), dim3(256), 0, stream>>>(Xtrain, bsq);
    knn_approx<<<dim3((N_TEST / TM) * NCHUNK), dim3(512), 0, stream>>>(testBf, trainBf, bsq, cand);
    knn_refine<<<dim3(N_TEST / RPB), dim3(256), 0, stream>>>(Xtest, Xtrain, bsq, cand, out);
}

// Round 11
// 410.079 us; speedup vs baseline: 1.6334x; 1.3219x over previous
//
#include <hip/hip_runtime.h>
#include <hip/hip_bf16.h>

// KNN top-16: X_test[4096,256] vs X_train[65536,256], fp32 in, int32 idx out.
// Phase 1: fp32->bf16 convert; fp32 train row sq-norms (numpy-pairwise emulation).
// Phase 2: bf16 MFMA approx score GEMM (v = ||b||^2 - 2 a.b), SWAPPED operands
//          (R10: mfma(train,test,acc) -> D[train_col][test_row], thread-local
//          per-row top-16 in registers, FETCH 25MB, zero selection syncs).
//          R10 post-mortem: VALUBusy 77% = per-slot guarded insertion executes
//          its ~34-op body for ~27/32 slots/iter at ~1/64 lane utilization
//          (any-of-64-lanes divergence). R11: DEFERRED selection via 4-deep
//          register shift-FIFO (q0..q3, no runtime indexing -> no scratch):
//          per slot = fmaf + float-cmp vs cached cut (+1024 folded into sBsq,
//          R8-verified superset pretest (lk15&~0xFFF)+0x1000); pass -> cheap
//          shift+pack body (rare overflow guard chain-inserts q3); ONCE per
//          iter: flush = 4 fixed-position guarded chain-inserts (~half the
//          lanes active -> divergence amortized), then cut refresh.
//          Chunk-end exact merge of 4 quad-partitions via shfl_xor bitonic
//          (R10-proven). GEMM/staging/syncs byte-identical to R10.
// Phase 3: 8 rows/block: approx-top-32 prefilter of 256 candidates (width-32
//          shuffles), then 256 parallel exact fp32-reference-emulating chains,
//          lex (d32, gidx) top-16 (fp32 snap-ties resolve by index like top_k).

typedef short bf16x8 __attribute__((ext_vector_type(8)));
typedef float f32x4 __attribute__((ext_vector_type(4)));
typedef unsigned short ushort_t;
typedef unsigned long long u64;

#define K_DIM     256
#define N_TRAIN   65536
#define N_TEST    4096
#define TM        128
#define TN        128
#define NCHUNK    16
#define CHUNK_N   (N_TRAIN / NCHUNK)      // 4096
#define ITERS     (CHUNK_N / TN)          // 32
#define LISTN     16
#define RPB       8                        // refine rows per block
#define SENT      0xFFFFFFFFu

// ---------------- numpy pairwise sum emulation (fp32, contract OFF) ----------------
static __device__ __forceinline__ float np_pw_sq128(const float* __restrict__ x) {
    #pragma clang fp contract(off)
    float r0, r1, r2, r3, r4, r5, r6, r7;
    {
        const float4 a = *(const float4*)(x + 0);
        const float4 b = *(const float4*)(x + 4);
        r0 = a.x * a.x; r1 = a.y * a.y; r2 = a.z * a.z; r3 = a.w * a.w;
        r4 = b.x * b.x; r5 = b.y * b.y; r6 = b.z * b.z; r7 = b.w * b.w;
    }
    for (int i = 8; i < 128; i += 8) {
        const float4 a = *(const float4*)(x + i);
        const float4 b = *(const float4*)(x + i + 4);
        r0 = r0 + a.x * a.x; r1 = r1 + a.y * a.y;
        r2 = r2 + a.z * a.z; r3 = r3 + a.w * a.w;
        r4 = r4 + b.x * b.x; r5 = r5 + b.y * b.y;
        r6 = r6 + b.z * b.z; r7 = r7 + b.w * b.w;
    }
    return ((r0 + r1) + (r2 + r3)) + ((r4 + r5) + (r6 + r7));
}

// ---------------- async global->LDS, 16B per lane ----------------
static __device__ __forceinline__ void gld_lds16(const ushort_t* g, ushort_t* l) {
    __builtin_amdgcn_global_load_lds(
        (const __attribute__((address_space(1))) unsigned int*)g,
        (__attribute__((address_space(3))) unsigned int*)l,
        16, 0, 0);
}

// ---------------- Phase 1a: convert ----------------
static __device__ __forceinline__ ushort_t f2bf(float x) {
    unsigned u = __float_as_uint(x);
    return (ushort_t)((u + 0x7FFFu + ((u >> 16) & 1u)) >> 16);  // RNE
}

__global__ __launch_bounds__(256) void convert_bf16(
    const float* __restrict__ src, ushort_t* __restrict__ dst, int nrows)
{
    const int wid = threadIdx.x >> 6, lane = threadIdx.x & 63;
    const int row = blockIdx.x * 4 + wid;
    if (row >= nrows) return;
    const float4 f = *(const float4*)(src + (size_t)row * K_DIM + lane * 4);
    ushort4 h;
    h.x = f2bf(f.x); h.y = f2bf(f.y); h.z = f2bf(f.z); h.w = f2bf(f.w);
    *(ushort4*)(dst + (size_t)row * K_DIM + lane * 4) = h;
}

// ---------------- Phase 1b: train row norms, numpy-pairwise fp32 ----------------
__global__ __launch_bounds__(256) void train_sq_np(
    const float* __restrict__ train, float* __restrict__ bsq)
{
    const int r = blockIdx.x * 256 + threadIdx.x;
    const float* x = train + (size_t)r * K_DIM;
    bsq[r] = np_pw_sq128(x) + np_pw_sq128(x + 128);
}

// ---------------- Phase 2: swapped-operand GEMM + FIFO-deferred register top-16 ----------------
// 512 thr, 8 waves; each wave owns 16 test rows x 128 train cols. B (train) staged
// in 32 KB LDS exactly as R4/R10; A (test) preloaded; D[train_col][test_row].
__global__ __launch_bounds__(512, 4) void knn_approx(
    const ushort_t* __restrict__ testBf, const ushort_t* __restrict__ trainBf,
    const float* __restrict__ bsq, unsigned* __restrict__ cand)
{
    __shared__ __align__(16) ushort_t sB[TN * 128];    // 32 KB: 128 cols x 128 k
    __shared__ __align__(16) float    sBsq[TN];        // 512 B (bsq + 1024)

    const int tid = threadIdx.x;
    const int bx = blockIdx.x;
    const int chunk = bx & (NCHUNK - 1);               // bx%8 = chunk%8 -> chunk-per-XCD
    const int rowTile = bx >> 4;                       // 0..31
    const int rowBase = rowTile * TM;
    const int chunkBase = chunk * CHUNK_N;
    const int lane = tid & 63;
    const int wid = tid >> 6;                          // 0..7
    const int quad = lane >> 4;
    const int l15 = lane & 15;

    // my test row (one per thread; 16 rows per wave, 8 waves = 128 rows)
    const int myRow = rowBase + wid * 16 + l15;

    // register-resident top-16 (packed keys), ascending; sentinels > any real key
    // and safe for the +0x1000 pretest reconstruction (0x7F7FF000+0x1000 = +inf).
    unsigned lk[LISTN];
    #pragma unroll
    for (int j = 0; j < LISTN; ++j) lk[j] = 0x7F7FF000u | (unsigned)j;

    // guarded chain-insert (compile-time indices only; SENT always fails guard)
    auto cins = [&](unsigned k) {
        if (k < lk[LISTN - 1]) {
            lk[LISTN - 1] = k;
            #pragma unroll
            for (int j = LISTN - 1; j > 0; --j)
                if (lk[j] < lk[j - 1]) {
                    const unsigned t = lk[j]; lk[j] = lk[j - 1]; lk[j - 1] = t;
                }
        }
    };

    // 4-deep shift FIFO of pending keys + cached float pretest cut
    unsigned q0 = SENT, q1 = SENT, q2 = SENT, q3 = SENT;
    float cutFp = __uint_as_float((lk[LISTN - 1] & 0xFFFFF000u) + 0x1000u);  // +inf

    // ---- preload A-fragments (test row myRow, all K=256; 8 frags = 32 VGPR) ----
    bf16x8 af[2][4];   // [panel][s2]; frag k = quad*8 + s2*32 + p*128
    {
        const ushort_t* a0 = testBf + (size_t)myRow * K_DIM + quad * 8;
        #pragma unroll
        for (int p = 0; p < 2; ++p)
            #pragma unroll
            for (int s2 = 0; s2 < 4; ++s2)
                af[p][s2] = *(const bf16x8*)(a0 + p * 128 + s2 * 32);
    }

    // B staging (R4-identical): slot s = c*512+tid -> col = c*32 + (tid>>4)
    const int rt = tid >> 4;                           // 0..31
    const int ub = tid & 15;
    const int kg = ((ub & 7) ^ (rt & 7)) | (ub & 8);   // c-independent (32%8==0)

    for (int it = 0; it < ITERS; ++it) {
        const int colBase = chunkBase + it * TN;
        f32x4 acc[8] = {};                             // 8 ct-tiles x 4 cols, my row

        #pragma unroll
        for (int p = 0; p < 2; ++p) {
            __syncthreads();           // protect sB against prior panel's reads
            {
                const ushort_t* gb = trainBf + (size_t)(colBase + rt) * K_DIM + p * 128 + kg * 8;
                ushort_t* lb = sB + (size_t)tid * 8;
                #pragma unroll
                for (int c = 0; c < 4; ++c)
                    gld_lds16(gb + (size_t)c * 32 * K_DIM, lb + (size_t)c * 4096);
            }
            if (p == 0 && tid < TN) sBsq[tid] = bsq[colBase + tid] + 1024.0f;
            __syncthreads();           // drains vmcnt -> LDS valid

            #pragma unroll
            for (int s2 = 0; s2 < 4; ++s2) {
                #pragma unroll
                for (int ct = 0; ct < 8; ++ct) {
                    const int col = ct * 16 + l15;     // train col (A-operand row)
                    const int g = s2 * 4 + quad;
                    const int pg = ((g & 7) ^ (col & 7)) | (g & 8);
                    const bf16x8 bfr = *(const bf16x8*)(sB + (size_t)col * 128 + pg * 8);
                    // SWAPPED: train as A, test as B -> D[train_col][test_row]
                    acc[ct] = __builtin_amdgcn_mfma_f32_16x16x32_bf16(bfr, af[p][s2], acc[ct], 0, 0, 0);
                }
            }
        }

        // epilogue: v+1024 = fmaf(-2, dot, bsq+1024); float pretest + FIFO push
        #pragma unroll
        for (int ct = 0; ct < 8; ++ct) {
            const float4 bq4 = *(const float4*)(sBsq + ct * 16 + quad * 4);
            const unsigned colb = (unsigned)(it * TN + ct * 16 + quad * 4);
            #pragma unroll
            for (int r = 0; r < 4; ++r) {
                const float bq = (r == 0) ? bq4.x : (r == 1) ? bq4.y : (r == 2) ? bq4.z : bq4.w;
                const float v = fmaf(-2.0f, acc[ct][r], bq);
                if (v < cutFp) {                       // 1-op pretest (superset of exact)
                    cins(q3);                          // overflow-preserve (rare; SENT fails)
                    q3 = q2; q2 = q1; q1 = q0;
                    q0 = (__float_as_uint(v) & 0xFFFFF000u) | (colb + (unsigned)r);
                }
            }
        }

        // flush FIFO (oldest first); ~half the lanes active -> amortized divergence
        cins(q3); cins(q2); cins(q1); cins(q0);
        q0 = SENT; q1 = SENT; q2 = SENT; q3 = SENT;
        cutFp = __uint_as_float((lk[LISTN - 1] & 0xFFFFF000u) + 0x1000u);
    }

    // ---- merge the 4 quad-partitions of my row (exact): shfl_xor 16 then 32 ----
    #pragma unroll
    for (int step = 16; step <= 32; step <<= 1) {
        unsigned other[LISTN];
        #pragma unroll
        for (int j = 0; j < LISTN; ++j)
            other[j] = (unsigned)__shfl_xor((int)lk[j], step, 64);
        unsigned c[LISTN];
        // half-cleaner: smallest 16 of (lk ∪ other); result is bitonic
        #pragma unroll
        for (int j = 0; j < LISTN; ++j) {
            const unsigned a = lk[j], b = other[LISTN - 1 - j];
            c[j] = a < b ? a : b;
        }
        // bitonic sort of a bitonic sequence: stages d = 8,4,2,1
        #pragma unroll
        for (int d = 8; d >= 1; d >>= 1)
            #pragma unroll
            for (int j = 0; j < LISTN; ++j)
                if ((j & d) == 0) {
                    const unsigned x = c[j], y = c[j | d];
                    c[j] = x < y ? x : y;
                    c[j | d] = x < y ? y : x;
                }
        #pragma unroll
        for (int j = 0; j < LISTN; ++j) lk[j] = c[j];
    }

    // quad 0 lanes hold the final sorted top-16 for their row
    if (lane < 16) {
        unsigned* dst = cand + (size_t)myRow * (NCHUNK * LISTN) + chunk * LISTN;
        #pragma unroll
        for (int j = 0; j < LISTN; ++j) dst[j] = lk[j];
    }
}

// ---------------- Phase 3: prefilter 256->32 + parallel exact fp32 re-rank ----------------
// 8 rows/block, 32 lanes/row; width-32 shuffles.
__global__ __launch_bounds__(256) void knn_refine(
    const float* __restrict__ test, const float* __restrict__ train,
    const float* __restrict__ bsq, const unsigned* __restrict__ cand,
    int* __restrict__ out)
{
    __shared__ __align__(16) float sArow[RPB * K_DIM];   // 8 KB
    __shared__ int sSel[RPB * 32];                       // 1 KB

    const int tid = threadIdx.x;
    const int rowBase = blockIdx.x * RPB;
    const int r = tid >> 5;          // row 0..7
    const int sub = tid & 31;        // lane within row

    {
        const float4* src = (const float4*)(test + (size_t)rowBase * K_DIM);
        float4* dst = (float4*)sArow;
        dst[tid] = src[tid];
        dst[256 + tid] = src[256 + tid];
    }

    u64 ek[8];
    {
        const unsigned* cp = cand + (size_t)(rowBase + r) * 256 + sub * 8;
        #pragma unroll
        for (int j = 0; j < 8; ++j) {
            const unsigned k = cp[j];
            const int chunkId = (sub * 8 + j) >> 4;
            const unsigned gidx = (unsigned)(chunkId * CHUNK_N) + (k & 0xFFFu);
            ek[j] = ((u64)(k & 0xFFFFF000u) << 8) | gidx;
        }
    }
    __syncthreads();

    for (int sel = 0; sel < 32; ++sel) {
        u64 bk = ek[0];
        #pragma unroll
        for (int j = 1; j < 8; ++j) bk = (ek[j] < bk) ? ek[j] : bk;
        #pragma unroll
        for (int off = 16; off > 0; off >>= 1) {
            const u64 ok = __shfl_xor(bk, off, 32);
            bk = (ok < bk) ? ok : bk;
        }
        if (sub == 0) sSel[r * 32 + sel] = (int)(bk & 0xFFFFULL);
        #pragma unroll
        for (int j = 0; j < 8; ++j)
            if (ek[j] == bk) ek[j] = ~0ULL;
    }
    __syncthreads();

    const int gidx = sSel[r * 32 + sub];
    const float* arow = sArow + r * K_DIM;
    const float ta = np_pw_sq128(arow) + np_pw_sq128(arow + 128);
    const float tb = bsq[gidx];

    const float4* bp = (const float4*)(train + (size_t)gidx * K_DIM);
    const float4* ap = (const float4*)arow;
    float c = 0.0f;
    #pragma unroll 8
    for (int k = 0; k < K_DIM / 4; ++k) {
        const float4 a = ap[k];
        const float4 b = bp[k];
        c = fmaf(a.x, b.x, c); c = fmaf(a.y, b.y, c);
        c = fmaf(a.z, b.z, c); c = fmaf(a.w, b.w, c);
    }
    float d32;
    {
        #pragma clang fp contract(off)
        const float t = ta + tb;
        float s = t - 2.0f * c;
        s = fmaxf(s, 0.0f);
        d32 = sqrtf(s);
    }

    u64 fk = ((u64)__float_as_uint(d32) << 32) | (unsigned)gidx;
    for (int sel = 0; sel < 16; ++sel) {
        u64 bk = fk;
        #pragma unroll
        for (int off = 16; off > 0; off >>= 1) {
            const u64 ok = __shfl_xor(bk, off, 32);
            bk = (ok < bk) ? ok : bk;
        }
        if (sub == 0) out[(size_t)(rowBase + r) * 16 + sel] = (int)(bk & 0xFFFFFFFFULL);
        if (fk == bk) fk = ~0ULL;
    }
}

// ---------------- launch ----------------
extern "C" void kernel_launch(void* const* d_in, const int* in_sizes, int n_in,
                              void* d_out, int out_size, void* d_ws, size_t ws_size,
                              hipStream_t stream)
{
    const float* Xtrain = (const float*)d_in[0];   // [65536, 256]
    const float* Xtest  = (const float*)d_in[1];   // [4096, 256]
    int* out = (int*)d_out;                        // [4096, 16] int32

    const size_t OFF_TRAINBF = 0;                              // 33,554,432 B
    const size_t OFF_TESTBF  = 33554432;                       //  2,097,152 B
    const size_t OFF_BSQ     = 35651584;                       //    262,144 B
    const size_t OFF_CAND    = 35913728;                       //  4,194,304 B
    const size_t NEED        = 40108032;
    if (ws_size < NEED) return;

    char* ws = (char*)d_ws;
    ushort_t* trainBf = (ushort_t*)(ws + OFF_TRAINBF);
    ushort_t* testBf  = (ushort_t*)(ws + OFF_TESTBF);
    float*    bsq     = (float*)(ws + OFF_BSQ);
    unsigned* cand    = (unsigned*)(ws + OFF_CAND);

    convert_bf16<<<dim3(N_TRAIN / 4), dim3(256), 0, stream>>>(Xtrain, trainBf, N_TRAIN);
    convert_bf16<<<dim3(N_TEST / 4), dim3(256), 0, stream>>>(Xtest, testBf, N_TEST);
    train_sq_np<<<dim3(N_TRAIN / 256), dim3(256), 0, stream>>>(Xtrain, bsq);
    knn_approx<<<dim3((N_TEST / TM) * NCHUNK), dim3(512), 0, stream>>>(testBf, trainBf, bsq, cand);
    knn_refine<<<dim3(N_TEST / RPB), dim3(256), 0, stream>>>(Xtest, Xtrain, bsq, cand, out);
}